// Round 4
// baseline (1265.415 us; speedup 1.0000x reference)
//
#include <hip/hip_runtime.h>

#define T_STEPS 512
#define BATCH   512
#define HID     128

typedef _Float16 h2 __attribute__((ext_vector_type(2)));
typedef _Float16 h4 __attribute__((ext_vector_type(4)));
typedef _Float16 v8hf __attribute__((ext_vector_type(8)));
typedef float v4f __attribute__((ext_vector_type(4)));

__device__ __forceinline__ float rcpf(float x) {
#if __has_builtin(__builtin_amdgcn_rcpf)
  return __builtin_amdgcn_rcpf(x);
#else
  return 1.0f / x;
#endif
}
__device__ __forceinline__ float sigm(float x)  { return rcpf(1.0f + __expf(-x)); }
__device__ __forceinline__ float tanh_f(float x){ return 1.0f - 2.0f * rcpf(__expf(2.0f * x) + 1.0f); }

// barrier WITHOUT vmcnt drain (CK block_sync_lds idiom): orders LDS only;
// per-wave global-load deps are auto-waited by the compiler at consumption.
__device__ __forceinline__ void sync_lds() {
  asm volatile("s_waitcnt lgkmcnt(0)\ns_barrier" ::: "memory");
}

// ---------------------------------------------------------------- prep ----
// Weight rows packed gate-interleaved: row' = 4*sd + gate  (orig row = gate*128+sd)
__global__ __launch_bounds__(256) void prep_w(
    const float* __restrict__ Wih0, const float* __restrict__ Whh0,
    const float* __restrict__ bih0, const float* __restrict__ bhh0,
    const float* __restrict__ Wih1, const float* __restrict__ Whh1,
    const float* __restrict__ bih1, const float* __restrict__ bhh1,
    _Float16* __restrict__ Wcat0, _Float16* __restrict__ Wcat1,
    float* __restrict__ bias0, float* __restrict__ bias1) {
  int i = blockIdx.x * blockDim.x + threadIdx.x;
  if (i < 512 * 192) {                  // Wcat0 row r': [Wih0(64) | Whh0(128)]
    int r = i / 192, k = i - r * 192;
    int orig = (r & 3) * 128 + (r >> 2);
    float v = (k < 64) ? Wih0[orig * 64 + k] : Whh0[orig * 128 + (k - 64)];
    Wcat0[i] = (_Float16)v;
  }
  if (i < 512 * 256) {                  // Wcat1 row r': [Wih1(128) | Whh1(128)]
    int r = i >> 8, k = i & 255;
    int orig = (r & 3) * 128 + (r >> 2);
    float v = (k < 128) ? Wih1[orig * 128 + k] : Whh1[orig * 128 + (k - 128)];
    Wcat1[i] = (_Float16)v;
  }
  if (i < 512) {
    int orig = (i & 3) * 128 + (i >> 2);
    bias0[i] = bih0[orig] + bhh0[orig];
    bias1[i] = bih1[orig] + bhh1[orig];
  }
}

// ------------------------------------------------------------- layer 0 ----
// 256 blocks x 512 threads (8 waves), 2 chains/block. v = [x(64)|h(128)], K=192.
// Gate-interleaved rows; in-lane activation from MFMA acc; 1 barrier/step.
__global__ __launch_bounds__(512, 2) void lstm_l0(
    const float*    __restrict__ x,     // [B][T][64] fp32
    const _Float16* __restrict__ Wcat,  // [512][192] packed rows
    const float*    __restrict__ bias,  // [512] packed
    _Float16*       __restrict__ hs0) { // [B][T][128]
  __shared__ __align__(16) _Float16 vbuf[2][2][192];  // [buf][chain][x|h]
  const int tid  = threadIdx.x;
  const int lane = tid & 63;
  const int wv   = tid >> 6;          // 0..7
  const int m    = lane & 15;         // A row within tile / B col
  const int q    = lane >> 4;         // k-group / C row-quad
  const int b0   = blockIdx.x * 2;
  const int ch   = m & 1;             // chain this column carries
  const int iact = (m >> 1) & 3;      // i-tile this lane activates
  const int sd   = 16 * wv + 4 * iact + q;  // hidden unit this lane owns

  // A fragments: af[i][kt], rt = 4*wv + i, K=192 (6 k-tiles)
  v8hf af[4][6];
  #pragma unroll
  for (int i = 0; i < 4; ++i) {
    const int rt = wv * 4 + i;
    #pragma unroll
    for (int kt = 0; kt < 6; ++kt)
      af[i][kt] = *(const v8hf*)&Wcat[(rt * 16 + m) * 192 + kt * 32 + q * 8];
  }
  // bias in MFMA C layout: row = (wv*4+i)*16 + q*4 + reg
  v4f cinit[4];
  #pragma unroll
  for (int i = 0; i < 4; ++i) {
    float4 b4 = *(const float4*)&bias[(wv * 4 + i) * 16 + q * 4];
    cinit[i][0] = b4.x; cinit[i][1] = b4.y; cinit[i][2] = b4.z; cinit[i][3] = b4.w;
  }

  // prefetch lanes: waves 0,1 lanes 32..47; 16 lanes x float4 per chain
  const bool ispf = (wv < 2) && (lane >= 32) && (lane < 48);
  const int  pid  = wv * 16 + (lane - 32);
  const int  pch  = (pid >> 4) & 1, poff = pid & 15;
  const float* pfbase = x + ((size_t)(b0 + pch) * T_STEPS) * 64 + poff * 4;

  if (tid < 256) vbuf[0][tid >> 7][64 + (tid & 127)] = (_Float16)0.0f;  // h(-1)=0
  float4 xreg;
  if (ispf) {
    float4 v0 = *(const float4*)(pfbase);            // x(0)
    h4 o; o[0] = (_Float16)v0.x; o[1] = (_Float16)v0.y;
          o[2] = (_Float16)v0.z; o[3] = (_Float16)v0.w;
    *(h4*)&vbuf[0][pch][poff * 4] = o;
    xreg = *(const float4*)(pfbase + 64);            // x(1)
  }
  sync_lds();

  float c_state = 0.0f;

  for (int t = 0; t < T_STEPS; ++t) {
    const int p = t & 1, nb = p ^ 1;
    if (ispf) {
      if (t + 1 < T_STEPS) {        // loaded a full step ago; vmcnt waited here
        h4 o; o[0] = (_Float16)xreg.x; o[1] = (_Float16)xreg.y;
              o[2] = (_Float16)xreg.z; o[3] = (_Float16)xreg.w;
        *(h4*)&vbuf[nb][pch][poff * 4] = o;
      }
      if (t + 2 < T_STEPS)
        xreg = *(const float4*)(pfbase + (size_t)(t + 2) * 64);
    }

    v4f acc[4];
    #pragma unroll
    for (int i = 0; i < 4; ++i) acc[i] = cinit[i];
    #pragma unroll
    for (int kt = 0; kt < 6; ++kt) {
      v8hf bfr = *(const v8hf*)&vbuf[p][ch][kt * 32 + q * 8];
      #pragma unroll
      for (int i = 0; i < 4; ++i)
        acc[i] = __builtin_amdgcn_mfma_f32_16x16x32_f16(af[i][kt], bfr, acc[i], 0, 0, 0);
    }

    // in-lane activation: this lane owns (chain=ch, hidden=sd) via acc[iact]
    const float gi = acc[iact][0];
    const float gf = acc[iact][1];
    const float gg = acc[iact][2];
    const float go = acc[iact][3];
    c_state = sigm(gf) * c_state + sigm(gi) * tanh_f(gg);
    const float hval = sigm(go) * tanh_f(c_state);
    if (m < 8) {                    // one writer per (ch, sd)
      const _Float16 hh = (_Float16)hval;
      vbuf[nb][ch][64 + sd] = hh;
      hs0[((size_t)(b0 + ch) * T_STEPS + t) * HID + sd] = hh;
    }
    sync_lds();                     // h(t), x(t+1) in buf nb visible
  }
}

// ------------------------------------------------------------- layer 1 ----
// v = [h0(128) | h1(128)], K=256 (8 k-tiles)
__global__ __launch_bounds__(512, 2) void lstm_l1(
    const _Float16* __restrict__ hs0,   // [B][T][128]
    const _Float16* __restrict__ Wcat,  // [512][256] packed rows
    const float*    __restrict__ bias,  // [512] packed
    float*          __restrict__ h2last) { // [B][128] fp32
  __shared__ __align__(16) _Float16 vbuf[2][2][256];
  const int tid  = threadIdx.x;
  const int lane = tid & 63;
  const int wv   = tid >> 6;
  const int m    = lane & 15;
  const int q    = lane >> 4;
  const int b0   = blockIdx.x * 2;
  const int ch   = m & 1;
  const int iact = (m >> 1) & 3;
  const int sd   = 16 * wv + 4 * iact + q;

  v8hf af[4][8];
  #pragma unroll
  for (int i = 0; i < 4; ++i) {
    const int rt = wv * 4 + i;
    #pragma unroll
    for (int kt = 0; kt < 8; ++kt)
      af[i][kt] = *(const v8hf*)&Wcat[(rt * 16 + m) * 256 + kt * 32 + q * 8];
  }
  v4f cinit[4];
  #pragma unroll
  for (int i = 0; i < 4; ++i) {
    float4 b4 = *(const float4*)&bias[(wv * 4 + i) * 16 + q * 4];
    cinit[i][0] = b4.x; cinit[i][1] = b4.y; cinit[i][2] = b4.z; cinit[i][3] = b4.w;
  }

  // prefetch lanes: waves 0,1 lanes 32..47; 16 lanes x 8 halfs per chain
  const bool ispf = (wv < 2) && (lane >= 32) && (lane < 48);
  const int  pid  = wv * 16 + (lane - 32);
  const int  pch  = (pid >> 4) & 1, poff = pid & 15;
  const _Float16* pfbase = hs0 + ((size_t)(b0 + pch) * T_STEPS) * HID + poff * 8;

  if (tid < 256) vbuf[0][tid >> 7][128 + (tid & 127)] = (_Float16)0.0f;  // h1(-1)=0
  v8hf xreg;
  if (ispf) {
    *(v8hf*)&vbuf[0][pch][poff * 8] = *(const v8hf*)(pfbase);  // h0(0)
    xreg = *(const v8hf*)(pfbase + HID);                       // h0(1)
  }
  sync_lds();

  float c_state = 0.0f;

  for (int t = 0; t < T_STEPS; ++t) {
    const int p = t & 1, nb = p ^ 1;
    if (ispf) {
      if (t + 1 < T_STEPS) *(v8hf*)&vbuf[nb][pch][poff * 8] = xreg;
      if (t + 2 < T_STEPS) xreg = *(const v8hf*)(pfbase + (size_t)(t + 2) * HID);
    }

    v4f acc[4];
    #pragma unroll
    for (int i = 0; i < 4; ++i) acc[i] = cinit[i];
    #pragma unroll
    for (int kt = 0; kt < 8; ++kt) {
      v8hf bfr = *(const v8hf*)&vbuf[p][ch][kt * 32 + q * 8];
      #pragma unroll
      for (int i = 0; i < 4; ++i)
        acc[i] = __builtin_amdgcn_mfma_f32_16x16x32_f16(af[i][kt], bfr, acc[i], 0, 0, 0);
    }

    const float gi = acc[iact][0];
    const float gf = acc[iact][1];
    const float gg = acc[iact][2];
    const float go = acc[iact][3];
    c_state = sigm(gf) * c_state + sigm(gi) * tanh_f(gg);
    const float hval = sigm(go) * tanh_f(c_state);
    if (m < 8) {
      vbuf[nb][ch][128 + sd] = (_Float16)hval;
      if (t == T_STEPS - 1) h2last[(size_t)(b0 + ch) * HID + sd] = hval;
    }
    sync_lds();
  }
}

// ------------------------------------------------------------- fc head ----
__global__ __launch_bounds__(128) void fc_head(
    const float* __restrict__ h2last, const float* __restrict__ fc1w,
    const float* __restrict__ fc1b, const float* __restrict__ fc2w,
    const float* __restrict__ fc2b, float* __restrict__ out) {
  __shared__ float hb[128];
  __shared__ float part[2];
  const int b = blockIdx.x, j = threadIdx.x;
  hb[j] = h2last[(size_t)b * HID + j];
  __syncthreads();
  const float* wr = fc1w + j * HID;
  float acc = 0.f;
  #pragma unroll 8
  for (int d = 0; d < HID; ++d) acc += wr[d] * hb[d];
  float v = fmaxf(acc + fc1b[j], 0.f) * fc2w[j];
  #pragma unroll
  for (int s = 32; s > 0; s >>= 1) v += __shfl_down(v, s);
  if ((j & 63) == 0) part[j >> 6] = v;
  __syncthreads();
  if (j == 0) out[b] = part[0] + part[1] + fc2b[0];
}

// -------------------------------------------------------------- launch ----
extern "C" void kernel_launch(void* const* d_in, const int* in_sizes, int n_in,
                              void* d_out, int out_size, void* d_ws, size_t ws_size,
                              hipStream_t stream) {
  const float* x    = (const float*)d_in[0];
  const float* Wih0 = (const float*)d_in[1];
  const float* Whh0 = (const float*)d_in[2];
  const float* bih0 = (const float*)d_in[3];
  const float* bhh0 = (const float*)d_in[4];
  const float* Wih1 = (const float*)d_in[5];
  const float* Whh1 = (const float*)d_in[6];
  const float* bih1 = (const float*)d_in[7];
  const float* bhh1 = (const float*)d_in[8];
  const float* fc1w = (const float*)d_in[9];
  const float* fc1b = (const float*)d_in[10];
  const float* fc2w = (const float*)d_in[11];
  const float* fc2b = (const float*)d_in[12];
  float* out = (float*)d_out;

  char* ws = (char*)d_ws;
  const size_t OFF_HS0 = 0;                         // 512*512*128*2 = 64 MiB
  const size_t OFF_WC0 = 67108864;                  // 512*192*2
  const size_t OFF_WC1 = OFF_WC0 + 196608;          // 512*256*2
  const size_t OFF_B0  = OFF_WC1 + 262144;          // 512*4
  const size_t OFF_B1  = OFF_B0 + 2048;
  const size_t OFF_H2L = OFF_B1 + 2048;             // 512*128*4

  _Float16* hs0    = (_Float16*)(ws + OFF_HS0);
  _Float16* Wcat0  = (_Float16*)(ws + OFF_WC0);
  _Float16* Wcat1  = (_Float16*)(ws + OFF_WC1);
  float*    bias0  = (float*)(ws + OFF_B0);
  float*    bias1  = (float*)(ws + OFF_B1);
  float*    h2last = (float*)(ws + OFF_H2L);

  prep_w<<<512, 256, 0, stream>>>(Wih0, Whh0, bih0, bhh0, Wih1, Whh1, bih1, bhh1,
                                  Wcat0, Wcat1, bias0, bias1);
  lstm_l0<<<256, 512, 0, stream>>>(x, Wcat0, bias0, hs0);
  lstm_l1<<<256, 512, 0, stream>>>(hs0, Wcat1, bias1, h2last);
  fc_head<<<512, 128, 0, stream>>>(h2last, fc1w, fc1b, fc2w, fc2b, out);
}